// Round 2
// baseline (516.257 us; speedup 1.0000x reference)
//
#include <hip/hip_runtime.h>
#include <hip/hip_bf16.h>
#include <stdint.h>

// Problem constants: B=8, N=4096, C=512, K=V=512, H=8, hk=hv=64, M = B*N = 32768

typedef __attribute__((ext_vector_type(8))) short short8;
typedef __attribute__((ext_vector_type(4))) float f32x4;
typedef __attribute__((ext_vector_type(4))) unsigned short us4;

__device__ __forceinline__ unsigned short f2bf(float f) {
  union { float f; unsigned u; } v; v.f = f;
  unsigned r = v.u + 0x7FFFu + ((v.u >> 16) & 1u);  // RNE
  return (unsigned short)(r >> 16);
}
__device__ __forceinline__ float bf2f(unsigned short u) {
  union { unsigned u; float f; } v; v.u = ((unsigned)u) << 16;
  return v.f;
}
// pack 2 fp32 -> 2 bf16 (RNE) — emits v_cvt_pk_bf16_f32
__device__ __forceinline__ ushort2 pk2(float a, float b) {
  __hip_bfloat162 h = __float22bfloat162_rn(float2{a, b});
  return *reinterpret_cast<ushort2*>(&h);
}

// ---------------------------------------------------------------------------
// Transpose + bf16-convert the 4 weight matrices: Wt[w][out][in] = W[in][out]
__global__ void prep_w(const float* __restrict__ Wk, const float* __restrict__ Wq,
                       const float* __restrict__ Wv, const float* __restrict__ Wr,
                       unsigned short* __restrict__ Wt) {
  __shared__ float tile[64][65];
  const int t = threadIdx.x;
  const int bx = blockIdx.x, by = blockIdx.y, w = blockIdx.z;
  const float* W = (w == 0) ? Wk : (w == 1) ? Wq : (w == 2) ? Wv : Wr;
  unsigned short* O = Wt + (size_t)w * 512 * 512;
#pragma unroll
  for (int p = 0; p < 16; ++p) {
    int idx = p * 256 + t; int r = idx >> 6, c = idx & 63;
    tile[r][c] = W[(size_t)(by * 64 + r) * 512 + bx * 64 + c];
  }
  __syncthreads();
#pragma unroll
  for (int p = 0; p < 16; ++p) {
    int idx = p * 256 + t; int r = idx >> 6, c = idx & 63;
    O[(size_t)(bx * 64 + r) * 512 + by * 64 + c] = f2bf(tile[c][r]);
  }
}

// ---------------------------------------------------------------------------
// Projection GEMM, LDS-free: [32768 x 512] = A(fp32) @ W(bf16, B^T layout) + bias
// All MFMA fragments loaded straight from global (A: fp32 + cvt_pk; B: bf16, L2-resident).
// MODE 0: A = x + y, epilogue exp(), TRANSPOSED out (KeT[b][k][tok], bf16)
// MODE 1: A = y,      plain,          row-major out (Qp[tok][ch], bf16)
// MODE 2: A = x,      plain,          TRANSPOSED out (VT[b][v][tok], bf16)
template <int MODE>
__global__ __launch_bounds__(256) void gemm_proj(const float* __restrict__ A0, const float* __restrict__ A1,
                          const unsigned short* __restrict__ Bt, const float* __restrict__ bias,
                          unsigned short* __restrict__ Out) {
  const int t = threadIdx.x;
  const int l = t & 63, w = t >> 6;
  const int lr = l & 15, lg = l >> 4;
  const int wr = w >> 1, wc = w & 1;
  // bijective XCD swizzle: 1024 blocks, 8 XCDs -> each XCD gets 128 consecutive
  // (tm,tn)-lex blocks => the 4 tn-blocks sharing an A row-tile sit on ONE L2.
  const int bid = blockIdx.x;
  const int swz = (bid & 7) * 128 + (bid >> 3);
  const int tn = swz & 3, tm = swz >> 2;

  const float* Ab = A0 + (size_t)(tm * 128 + wr * 64) * 512;
  const float* Cb = (MODE == 0) ? (A1 + (size_t)(tm * 128 + wr * 64) * 512) : nullptr;
  const unsigned short* Bb = Bt + (size_t)(tn * 128 + wc * 64) * 512;

  f32x4 acc[4][4] = {};
  for (int kt = 0; kt < 8; ++kt) {
#pragma unroll
    for (int kk = 0; kk < 2; ++kk) {
      const int k0 = kt * 64 + kk * 32 + lg * 8;
      short8 af[4], bf[4];
#pragma unroll
      for (int m = 0; m < 4; ++m) {
        const float* p = Ab + (size_t)(m * 16 + lr) * 512 + k0;
        float4 a0 = *(const float4*)p;
        float4 a1 = *(const float4*)(p + 4);
        if (MODE == 0) {
          const float* q = Cb + (size_t)(m * 16 + lr) * 512 + k0;
          float4 b0 = *(const float4*)q;
          float4 b1 = *(const float4*)(q + 4);
          a0.x += b0.x; a0.y += b0.y; a0.z += b0.z; a0.w += b0.w;
          a1.x += b1.x; a1.y += b1.y; a1.z += b1.z; a1.w += b1.w;
        }
        ushort2 c0 = pk2(a0.x, a0.y), c1 = pk2(a0.z, a0.w);
        ushort2 c2 = pk2(a1.x, a1.y), c3 = pk2(a1.z, a1.w);
        short8 v;
        v[0] = (short)c0.x; v[1] = (short)c0.y; v[2] = (short)c1.x; v[3] = (short)c1.y;
        v[4] = (short)c2.x; v[5] = (short)c2.y; v[6] = (short)c3.x; v[7] = (short)c3.y;
        af[m] = v;
      }
#pragma unroll
      for (int n = 0; n < 4; ++n)
        bf[n] = *(const short8*)&Bb[(size_t)(n * 16 + lr) * 512 + k0];
#pragma unroll
      for (int m = 0; m < 4; ++m)
#pragma unroll
        for (int n = 0; n < 4; ++n)
          acc[m][n] = __builtin_amdgcn_mfma_f32_16x16x32_bf16(af[m], bf[n], acc[m][n], 0, 0, 0);
    }
  }

  // ---- epilogue ----
  const int c_base = tn * 128 + wc * 64;
  const int r_base = tm * 128 + wr * 64;
#pragma unroll
  for (int n = 0; n < 4; ++n) {
    const int col = c_base + n * 16 + lr;
    const float bs = bias[col];
#pragma unroll
    for (int m = 0; m < 4; ++m) {
      const int row = r_base + m * 16 + lg * 4;
      if (MODE == 1) {
#pragma unroll
        for (int j = 0; j < 4; ++j)
          Out[(size_t)(row + j) * 512 + col] = f2bf(acc[m][n][j] + bs);
      } else {
        const int b = row >> 12, nl = row & 4095;  // tile rows never cross a batch
        us4 v;
#pragma unroll
        for (int j = 0; j < 4; ++j) {
          float f = acc[m][n][j] + bs;
          if (MODE == 0) f = __expf(f);
          v[j] = f2bf(f);
        }
        *(us4*)&Out[((size_t)(b * 512 + col)) * 4096 + nl] = v;
      }
    }
  }
}

// ---------------------------------------------------------------------------
// In-place row softmax over 64 channels per (token, head). One wave per group.
__global__ void qsoftmax(unsigned short* __restrict__ Qp) {
  const int t = threadIdx.x, l = t & 63, w = t >> 6;
  const int gw = blockIdx.x * 4 + w;  // 0..4095
  for (int i = 0; i < 64; ++i) {
    const int g = gw * 64 + i;        // 0..262143
    const int m = g >> 3, h = g & 7;
    const size_t addr = (size_t)m * 512 + h * 64 + l;
    float x = bf2f(Qp[addr]);
    float mx = x;
#pragma unroll
    for (int o = 32; o; o >>= 1) mx = fmaxf(mx, __shfl_xor(mx, o));
    float e = __expf(x - mx);
    float s = e;
#pragma unroll
    for (int o = 32; o; o >>= 1) s += __shfl_xor(s, o);
    Qp[addr] = f2bf(e / s);
  }
}

// ---------------------------------------------------------------------------
// S[b*512+k] = sum over 4096 tokens of KeT row (key-softmax denominator)
__global__ void ssum(const unsigned short* __restrict__ KeT, float* __restrict__ S) {
  const int t = threadIdx.x;
  const int row = blockIdx.x;
  const unsigned short* p = KeT + (size_t)row * 4096 + t * 16;
  float s = 0.f;
#pragma unroll
  for (int q = 0; q < 2; ++q) {
    short8 v = *(const short8*)(p + q * 8);
#pragma unroll
    for (int j = 0; j < 8; ++j) s += bf2f((unsigned short)v[j]);
  }
#pragma unroll
  for (int o = 32; o; o >>= 1) s += __shfl_xor(s, o);
  __shared__ float ls[4];
  if ((t & 63) == 0) ls[t >> 6] = s;
  __syncthreads();
  if (t == 0) S[row] = ls[0] + ls[1] + ls[2] + ls[3];
}

// ---------------------------------------------------------------------------
// Partial context: D[v][k] = sum_tok VT[v][tok] * KeT[k][tok] over a 1024-token chunk.
__global__ void context_partial(const unsigned short* __restrict__ KeT,
                                const unsigned short* __restrict__ VT,
                                float* __restrict__ cp) {
  const int t = threadIdx.x, l = t & 63, w = t >> 6;
  const int lr = l & 15, lg = l >> 4;
  const int ch = blockIdx.x, h = blockIdx.y, b = blockIdx.z;
  const unsigned short* Kp = KeT + ((size_t)b * 512 + h * 64) * 4096;
  const unsigned short* Vp = VT + ((size_t)b * 512 + h * 64) * 4096;
  const int tok_w = ch * 1024 + w * 256;
  f32x4 acc[4][4] = {};
  for (int s = 0; s < 8; ++s) {
    const int tok = tok_w + s * 32 + lg * 8;
    short8 a[4], kf[4];
#pragma unroll
    for (int m = 0; m < 4; ++m) a[m] = *(const short8*)&Vp[(size_t)(m * 16 + lr) * 4096 + tok];
#pragma unroll
    for (int n = 0; n < 4; ++n) kf[n] = *(const short8*)&Kp[(size_t)(n * 16 + lr) * 4096 + tok];
#pragma unroll
    for (int m = 0; m < 4; ++m)
#pragma unroll
      for (int n = 0; n < 4; ++n)
        acc[m][n] = __builtin_amdgcn_mfma_f32_16x16x32_bf16(a[m], kf[n], acc[m][n], 0, 0, 0);
  }
  __shared__ float red[4][64][64];
#pragma unroll
  for (int m = 0; m < 4; ++m)
#pragma unroll
    for (int n = 0; n < 4; ++n)
#pragma unroll
      for (int j = 0; j < 4; ++j)
        red[w][m * 16 + lg * 4 + j][n * 16 + lr] = acc[m][n][j];
  __syncthreads();
  const int blk = (b * 8 + h) * 4 + ch;
  float* o = cp + (size_t)blk * 4096;
  for (int i = 0; i < 16; ++i) {
    int e = i * 256 + t;
    int v = e >> 6, k = e & 63;
    o[e] = red[0][v][k] + red[1][v][k] + red[2][v][k] + red[3][v][k];
  }
}

// Reduce 4 chunk-partials, normalize by S, store transposed: ctxN[bh][k][v] (bf16)
__global__ void ctx_reduce(const float* __restrict__ cp, const float* __restrict__ S,
                           unsigned short* __restrict__ ctxN) {
  const int bh = blockIdx.x, t = threadIdx.x;
  const float* p = cp + (size_t)bh * 4 * 4096;
  for (int i = 0; i < 16; ++i) {
    int e = i * 256 + t;
    float vsum = p[e] + p[4096 + e] + p[8192 + e] + p[12288 + e];
    int v = e >> 6, k = e & 63;
    ctxN[(size_t)bh * 4096 + k * 64 + v] = f2bf(vsum / S[bh * 64 + k]);
  }
}

// ---------------------------------------------------------------------------
// M[b][c][h*64+k] = sum_v ctxN[b,h][k][v] * Wr[h*64+v][c]   (transposed for final GEMM)
__global__ void ctx_mm(const unsigned short* __restrict__ ctxN, const unsigned short* __restrict__ Wrt,
                       unsigned short* __restrict__ MT) {
  const int t = threadIdx.x, l = t & 63, w = t >> 6;
  const int lr = l & 15, lg = l >> 4;
  const int h = blockIdx.x, b = blockIdx.y;
  const unsigned short* Ap = ctxN + (size_t)(b * 8 + h) * 4096;
  f32x4 acc[4][8] = {};
  const int c0 = w * 128;
#pragma unroll
  for (int kk = 0; kk < 2; ++kk) {
    const int vb = kk * 32 + lg * 8;
    short8 a[4], bfr[8];
#pragma unroll
    for (int m = 0; m < 4; ++m) a[m] = *(const short8*)&Ap[(m * 16 + lr) * 64 + vb];
#pragma unroll
    for (int n = 0; n < 8; ++n) bfr[n] = *(const short8*)&Wrt[(size_t)(c0 + n * 16 + lr) * 512 + h * 64 + vb];
#pragma unroll
    for (int m = 0; m < 4; ++m)
#pragma unroll
      for (int n = 0; n < 8; ++n)
        acc[m][n] = __builtin_amdgcn_mfma_f32_16x16x32_bf16(a[m], bfr[n], acc[m][n], 0, 0, 0);
  }
#pragma unroll
  for (int n = 0; n < 8; ++n) {
    const int c = c0 + n * 16 + lr;
#pragma unroll
    for (int m = 0; m < 4; ++m) {
      const int k = m * 16 + lg * 4;
      us4 v;
#pragma unroll
      for (int j = 0; j < 4; ++j) v[j] = f2bf(acc[m][n][j]);
      *(us4*)&MT[((size_t)b * 512 + c) * 512 + h * 64 + k] = v;
    }
  }
}

// ---------------------------------------------------------------------------
// Final GEMM, LDS-free: out[tok][c] = sum_j Qs[tok][j] * MT[b][c][j] + br[c]  (fp32 out)
__global__ __launch_bounds__(256) void gemm_final(const unsigned short* __restrict__ Qs,
                           const unsigned short* __restrict__ MT,
                           const float* __restrict__ br, float* __restrict__ out) {
  const int t = threadIdx.x, l = t & 63, w = t >> 6;
  const int lr = l & 15, lg = l >> 4;
  const int wr = w >> 1, wc = w & 1;
  const int bid = blockIdx.x;
  const int swz = (bid & 7) * 128 + (bid >> 3);
  const int tn = swz & 3, tm = swz >> 2;   // XCD x owns batch x exactly (32 tm per batch)

  const unsigned short* Abase = Qs + (size_t)(tm * 128 + wr * 64) * 512;
  const unsigned short* Bbase = MT + (size_t)(tm >> 5) * 512 * 512 + (size_t)(tn * 128 + wc * 64) * 512;

  f32x4 acc[4][4] = {};
  for (int kt = 0; kt < 8; ++kt) {
#pragma unroll
    for (int kk = 0; kk < 2; ++kk) {
      const int k0 = kt * 64 + kk * 32 + lg * 8;
      short8 af[4], bf[4];
#pragma unroll
      for (int m = 0; m < 4; ++m) af[m] = *(const short8*)&Abase[(size_t)(m * 16 + lr) * 512 + k0];
#pragma unroll
      for (int n = 0; n < 4; ++n) bf[n] = *(const short8*)&Bbase[(size_t)(n * 16 + lr) * 512 + k0];
#pragma unroll
      for (int m = 0; m < 4; ++m)
#pragma unroll
        for (int n = 0; n < 4; ++n)
          acc[m][n] = __builtin_amdgcn_mfma_f32_16x16x32_bf16(af[m], bf[n], acc[m][n], 0, 0, 0);
    }
  }
  const int c_base = tn * 128 + wc * 64;
  const int r_base = tm * 128 + wr * 64;
#pragma unroll
  for (int n = 0; n < 4; ++n) {
    const int col = c_base + n * 16 + lr;
    const float bs = br[col];
#pragma unroll
    for (int m = 0; m < 4; ++m) {
      const int row = r_base + m * 16 + lg * 4;
#pragma unroll
      for (int j = 0; j < 4; ++j)
        out[(size_t)(row + j) * 512 + col] = acc[m][n][j] + bs;
    }
  }
}

// ---------------------------------------------------------------------------
extern "C" void kernel_launch(void* const* d_in, const int* in_sizes, int n_in,
                              void* d_out, int out_size, void* d_ws, size_t ws_size,
                              hipStream_t stream) {
  (void)in_sizes; (void)n_in; (void)out_size; (void)ws_size;
  const float* x  = (const float*)d_in[0];
  const float* y  = (const float*)d_in[1];
  const float* Wk = (const float*)d_in[2];
  const float* bk = (const float*)d_in[3];
  const float* Wq = (const float*)d_in[4];
  const float* bq = (const float*)d_in[5];
  const float* Wv = (const float*)d_in[6];
  const float* bv = (const float*)d_in[7];
  const float* Wr = (const float*)d_in[8];
  const float* br = (const float*)d_in[9];
  float* out = (float*)d_out;

  char* ws = (char*)d_ws;
  unsigned short* Wt   = (unsigned short*)(ws + 0);            //  2 MB: 4x [512][512] bf16 (transposed)
  unsigned short* KeT  = (unsigned short*)(ws + 2097152);      // 32 MB: [B][512][4096] bf16
  unsigned short* VT   = (unsigned short*)(ws + 35651584);     // 32 MB: [B][512][4096] bf16
  unsigned short* Qp   = (unsigned short*)(ws + 69206016);     // 32 MB: [32768][512] bf16
  float* S             = (float*)(ws + 102760448);             // 16 KB
  float* cp            = (float*)(ws + 102776832);             //  4 MB
  unsigned short* ctxN = (unsigned short*)(ws + 106971136);    // .5 MB
  unsigned short* MT   = (unsigned short*)(ws + 107495424);    //  4 MB

  prep_w<<<dim3(8, 8, 4), 256, 0, stream>>>(Wk, Wq, Wv, Wr, Wt);
  gemm_proj<0><<<1024, 256, 0, stream>>>(x, y, Wt, bk, KeT);
  gemm_proj<2><<<1024, 256, 0, stream>>>(x, nullptr, Wt + 2 * 262144, bv, VT);
  gemm_proj<1><<<1024, 256, 0, stream>>>(y, nullptr, Wt + 262144, bq, Qp);
  qsoftmax<<<1024, 256, 0, stream>>>(Qp);
  ssum<<<4096, 256, 0, stream>>>(KeT, S);
  context_partial<<<dim3(4, 8, 8), 256, 0, stream>>>(KeT, VT, cp);
  ctx_reduce<<<64, 256, 0, stream>>>(cp, S, ctxN);
  ctx_mm<<<dim3(8, 8), 256, 0, stream>>>(ctxN, Wt + 3 * 262144, MT);
  gemm_final<<<1024, 256, 0, stream>>>(Qp, MT, br, out);
}

// Round 3
// 307.918 us; speedup vs baseline: 1.6766x; 1.6766x over previous
//
#include <hip/hip_runtime.h>
#include <hip/hip_bf16.h>
#include <stdint.h>

// Problem constants: B=8, N=4096, C=512, K=V=512, H=8, hk=hv=64, M = B*N = 32768

typedef __attribute__((ext_vector_type(8))) short short8;
typedef __attribute__((ext_vector_type(4))) float f32x4;
typedef __attribute__((ext_vector_type(4))) unsigned short us4;

__device__ __forceinline__ unsigned short f2bf(float f) {
  union { float f; unsigned u; } v; v.f = f;
  unsigned r = v.u + 0x7FFFu + ((v.u >> 16) & 1u);  // RNE
  return (unsigned short)(r >> 16);
}
__device__ __forceinline__ float bf2f(unsigned short u) {
  union { unsigned u; float f; } v; v.u = ((unsigned)u) << 16;
  return v.f;
}
__device__ __forceinline__ ushort2 pk2(float a, float b) {
  __hip_bfloat162 h = __float22bfloat162_rn(float2{a, b});
  return *reinterpret_cast<ushort2*>(&h);
}
// async global->LDS, 16B per lane; lds base must be wave-uniform (HW: base + lane*16)
__device__ __forceinline__ void gload16(const void* g, void* l) {
  __builtin_amdgcn_global_load_lds(
      (const __attribute__((address_space(1))) void*)g,
      (__attribute__((address_space(3))) void*)l, 16, 0, 0);
}

// ---------------------------------------------------------------------------
// Transpose + bf16-convert the 4 weight matrices: Wt[w][out][in] = W[in][out]
__global__ void prep_w(const float* __restrict__ Wk, const float* __restrict__ Wq,
                       const float* __restrict__ Wv, const float* __restrict__ Wr,
                       unsigned short* __restrict__ Wt) {
  __shared__ float tile[64][65];
  const int t = threadIdx.x;
  const int bx = blockIdx.x, by = blockIdx.y, w = blockIdx.z;
  const float* W = (w == 0) ? Wk : (w == 1) ? Wq : (w == 2) ? Wv : Wr;
  unsigned short* O = Wt + (size_t)w * 512 * 512;
#pragma unroll
  for (int p = 0; p < 16; ++p) {
    int idx = p * 256 + t; int r = idx >> 6, c = idx & 63;
    tile[r][c] = W[(size_t)(by * 64 + r) * 512 + bx * 64 + c];
  }
  __syncthreads();
#pragma unroll
  for (int p = 0; p < 16; ++p) {
    int idx = p * 256 + t; int r = idx >> 6, c = idx & 63;
    O[(size_t)(bx * 64 + r) * 512 + by * 64 + c] = f2bf(tile[c][r]);
  }
}

// ---------------------------------------------------------------------------
// Projection GEMM, prefetch-pipelined: [32768 x 512] = A(fp32) @ W(bf16 B^T) + bias
// A: reg-staged fp32 (async split: issue early, cvt+ds_write late). B: global_load_lds.
// LDS XOR-swizzled (slot ^= row&7, 16B granularity); B swizzle via pre-swizzled global src.
// MODE 0: A = x + y, epilogue exp(), TRANSPOSED out (KeT[b][k][tok], bf16)
// MODE 1: A = y,  epilogue fused head-softmax (over 64 ch), row-major out Qp
// MODE 2: A = x,  plain, TRANSPOSED out (VT[b][v][tok], bf16)
template <int MODE>
__global__ __launch_bounds__(256) void gemm_proj(const float* __restrict__ A0,
                          const float* __restrict__ A1,
                          const unsigned short* __restrict__ Bt, const float* __restrict__ bias,
                          unsigned short* __restrict__ Out) {
  __shared__ __align__(16) unsigned short As[2][128][64];
  __shared__ __align__(16) unsigned short Bs[2][128][64];
  const int t = threadIdx.x;
  const int l = t & 63, w = t >> 6;
  const int lr = l & 15, lg = l >> 4;
  const int wr = w >> 1, wc = w & 1;
  const int bid = blockIdx.x;
  const int swz = (bid & 7) * 128 + (bid >> 3);   // bijective XCD swizzle (1024 % 8 == 0)
  const int tn = swz & 3, tm = swz >> 2;

  // A reg-stage geometry: thread -> row ar (2 thr/row), 32 fp32 each
  const int ar = t >> 1, ah = t & 1;
  const float* Arow = A0 + (size_t)(tm * 128 + ar) * 512 + ah * 32;
  const float* Crow = (MODE == 0) ? (A1 + (size_t)(tm * 128 + ar) * 512 + ah * 32) : nullptr;

  // B gload geometry: lane l, wave w, issue i: row = w*32+i*8+(l>>3), colslot (l&7)^(l>>3)
  const unsigned short* Bg =
      Bt + (size_t)(tn * 128 + w * 32 + (l >> 3)) * 512 + ((l & 7) ^ (l >> 3)) * 8;

  f32x4 acc[4][4] = {};
  float4 xa[8], ya[8];

  // ---- prologue: tile 0 ----
#pragma unroll
  for (int i = 0; i < 4; ++i)
    gload16(Bg + (size_t)i * 8 * 512, &Bs[0][w * 32 + i * 8][0]);
#pragma unroll
  for (int j = 0; j < 8; ++j) {
    xa[j] = *(const float4*)(Arow + j * 4);
    if (MODE == 0) ya[j] = *(const float4*)(Crow + j * 4);
  }
#pragma unroll
  for (int i = 0; i < 4; ++i) {
    float4 u0 = xa[2 * i], u1 = xa[2 * i + 1];
    if (MODE == 0) {
      float4 v0 = ya[2 * i], v1 = ya[2 * i + 1];
      u0.x += v0.x; u0.y += v0.y; u0.z += v0.z; u0.w += v0.w;
      u1.x += v1.x; u1.y += v1.y; u1.z += v1.z; u1.w += v1.w;
    }
    ushort2 c0 = pk2(u0.x, u0.y), c1 = pk2(u0.z, u0.w);
    ushort2 c2 = pk2(u1.x, u1.y), c3 = pk2(u1.z, u1.w);
    short8 v;
    v[0] = (short)c0.x; v[1] = (short)c0.y; v[2] = (short)c1.x; v[3] = (short)c1.y;
    v[4] = (short)c2.x; v[5] = (short)c2.y; v[6] = (short)c3.x; v[7] = (short)c3.y;
    *(short8*)&As[0][ar][(((ah * 4 + i) ^ (ar & 7)) * 8)] = v;
  }
  __syncthreads();

  // ---- main loop: 8 K-steps, 2-phase ----
#pragma unroll 2
  for (int kt = 0; kt < 8; ++kt) {
    const int cur = kt & 1, nxt = cur ^ 1;
    int ktn = kt + 1; if (ktn > 7) ktn = 7;  // last-iter loads are redundant but in-bounds
    // issue next tile: B -> LDS direct, A -> regs
#pragma unroll
    for (int i = 0; i < 4; ++i)
      gload16(Bg + (size_t)i * 8 * 512 + ktn * 64, &Bs[nxt][w * 32 + i * 8][0]);
#pragma unroll
    for (int j = 0; j < 8; ++j) {
      xa[j] = *(const float4*)(Arow + ktn * 64 + j * 4);
      if (MODE == 0) ya[j] = *(const float4*)(Crow + ktn * 64 + j * 4);
    }
    // compute current tile
#pragma unroll
    for (int kk = 0; kk < 2; ++kk) {
      short8 af[4], bf[4];
#pragma unroll
      for (int m = 0; m < 4; ++m) {
        const int row = wr * 64 + m * 16 + lr;
        af[m] = *(const short8*)&As[cur][row][(((kk * 4 + lg) ^ (row & 7)) * 8)];
      }
#pragma unroll
      for (int n = 0; n < 4; ++n) {
        const int row = wc * 64 + n * 16 + lr;
        bf[n] = *(const short8*)&Bs[cur][row][(((kk * 4 + lg) ^ (row & 7)) * 8)];
      }
#pragma unroll
      for (int m = 0; m < 4; ++m)
#pragma unroll
        for (int n = 0; n < 4; ++n)
          acc[m][n] = __builtin_amdgcn_mfma_f32_16x16x32_bf16(af[m], bf[n], acc[m][n], 0, 0, 0);
    }
    // write next A tile (waits the reg loads; latency was covered by MFMA phase)
#pragma unroll
    for (int i = 0; i < 4; ++i) {
      float4 u0 = xa[2 * i], u1 = xa[2 * i + 1];
      if (MODE == 0) {
        float4 v0 = ya[2 * i], v1 = ya[2 * i + 1];
        u0.x += v0.x; u0.y += v0.y; u0.z += v0.z; u0.w += v0.w;
        u1.x += v1.x; u1.y += v1.y; u1.z += v1.z; u1.w += v1.w;
      }
      ushort2 c0 = pk2(u0.x, u0.y), c1 = pk2(u0.z, u0.w);
      ushort2 c2 = pk2(u1.x, u1.y), c3 = pk2(u1.z, u1.w);
      short8 v;
      v[0] = (short)c0.x; v[1] = (short)c0.y; v[2] = (short)c1.x; v[3] = (short)c1.y;
      v[4] = (short)c2.x; v[5] = (short)c2.y; v[6] = (short)c3.x; v[7] = (short)c3.y;
      *(short8*)&As[nxt][ar][(((ah * 4 + i) ^ (ar & 7)) * 8)] = v;
    }
    __syncthreads();  // drains gload vmcnt + ds_write lgkm; next tile ready
  }

  // ---- epilogue ----
  const int c_base = tn * 128 + wc * 64;
  const int r_base = tm * 128 + wr * 64;
  float bv_[4];
#pragma unroll
  for (int n = 0; n < 4; ++n) bv_[n] = bias[c_base + n * 16 + lr];

  if (MODE == 1) {
    // fused query-softmax over this wave's 64 cols (= one head). fp32 in-register.
#pragma unroll
    for (int m = 0; m < 4; ++m) {
#pragma unroll
      for (int j = 0; j < 4; ++j) {
        float a0 = acc[m][0][j] + bv_[0], a1 = acc[m][1][j] + bv_[1];
        float a2 = acc[m][2][j] + bv_[2], a3 = acc[m][3][j] + bv_[3];
        float mx = fmaxf(fmaxf(a0, a1), fmaxf(a2, a3));
#pragma unroll
        for (int o = 1; o < 16; o <<= 1) mx = fmaxf(mx, __shfl_xor(mx, o));
        float e0 = __expf(a0 - mx), e1 = __expf(a1 - mx);
        float e2 = __expf(a2 - mx), e3 = __expf(a3 - mx);
        float s = e0 + e1 + e2 + e3;
#pragma unroll
        for (int o = 1; o < 16; o <<= 1) s += __shfl_xor(s, o);
        const float rs = 1.0f / s;
        const int row = r_base + m * 16 + lg * 4 + j;
        Out[(size_t)row * 512 + c_base + 0 * 16 + lr] = f2bf(e0 * rs);
        Out[(size_t)row * 512 + c_base + 1 * 16 + lr] = f2bf(e1 * rs);
        Out[(size_t)row * 512 + c_base + 2 * 16 + lr] = f2bf(e2 * rs);
        Out[(size_t)row * 512 + c_base + 3 * 16 + lr] = f2bf(e3 * rs);
      }
    }
  } else {
#pragma unroll
    for (int n = 0; n < 4; ++n) {
      const int col = c_base + n * 16 + lr;
#pragma unroll
      for (int m = 0; m < 4; ++m) {
        const int row = r_base + m * 16 + lg * 4;
        const int b = row >> 12, nl = row & 4095;  // tile rows never cross a batch
        us4 v;
#pragma unroll
        for (int j = 0; j < 4; ++j) {
          float f = acc[m][n][j] + bv_[n];
          if (MODE == 0) f = __expf(f);
          v[j] = f2bf(f);
        }
        *(us4*)&Out[((size_t)(b * 512 + col)) * 4096 + nl] = v;
      }
    }
  }
}

// ---------------------------------------------------------------------------
// S[b*512+k] = sum over 4096 tokens of KeT row (key-softmax denominator)
__global__ void ssum(const unsigned short* __restrict__ KeT, float* __restrict__ S) {
  const int t = threadIdx.x;
  const int row = blockIdx.x;
  const unsigned short* p = KeT + (size_t)row * 4096 + t * 16;
  float s = 0.f;
#pragma unroll
  for (int q = 0; q < 2; ++q) {
    short8 v = *(const short8*)(p + q * 8);
#pragma unroll
    for (int j = 0; j < 8; ++j) s += bf2f((unsigned short)v[j]);
  }
#pragma unroll
  for (int o = 32; o; o >>= 1) s += __shfl_xor(s, o);
  __shared__ float ls[4];
  if ((t & 63) == 0) ls[t >> 6] = s;
  __syncthreads();
  if (t == 0) S[row] = ls[0] + ls[1] + ls[2] + ls[3];
}

// ---------------------------------------------------------------------------
// Partial context: D[v][k] = sum_tok VT[v][tok] * KeT[k][tok] over a 1024-token chunk.
__global__ void context_partial(const unsigned short* __restrict__ KeT,
                                const unsigned short* __restrict__ VT,
                                float* __restrict__ cp) {
  const int t = threadIdx.x, l = t & 63, w = t >> 6;
  const int lr = l & 15, lg = l >> 4;
  const int ch = blockIdx.x, h = blockIdx.y, b = blockIdx.z;
  const unsigned short* Kp = KeT + ((size_t)b * 512 + h * 64) * 4096;
  const unsigned short* Vp = VT + ((size_t)b * 512 + h * 64) * 4096;
  const int tok_w = ch * 1024 + w * 256;
  f32x4 acc[4][4] = {};
  for (int s = 0; s < 8; ++s) {
    const int tok = tok_w + s * 32 + lg * 8;
    short8 a[4], kf[4];
#pragma unroll
    for (int m = 0; m < 4; ++m) a[m] = *(const short8*)&Vp[(size_t)(m * 16 + lr) * 4096 + tok];
#pragma unroll
    for (int n = 0; n < 4; ++n) kf[n] = *(const short8*)&Kp[(size_t)(n * 16 + lr) * 4096 + tok];
#pragma unroll
    for (int m = 0; m < 4; ++m)
#pragma unroll
      for (int n = 0; n < 4; ++n)
        acc[m][n] = __builtin_amdgcn_mfma_f32_16x16x32_bf16(a[m], kf[n], acc[m][n], 0, 0, 0);
  }
  __shared__ float red[4][64][64];
#pragma unroll
  for (int m = 0; m < 4; ++m)
#pragma unroll
    for (int n = 0; n < 4; ++n)
#pragma unroll
      for (int j = 0; j < 4; ++j)
        red[w][m * 16 + lg * 4 + j][n * 16 + lr] = acc[m][n][j];
  __syncthreads();
  const int blk = (b * 8 + h) * 4 + ch;
  float* o = cp + (size_t)blk * 4096;
  for (int i = 0; i < 16; ++i) {
    int e = i * 256 + t;
    int v = e >> 6, k = e & 63;
    o[e] = red[0][v][k] + red[1][v][k] + red[2][v][k] + red[3][v][k];
  }
}

// Reduce 4 chunk-partials, normalize by S, store transposed: ctxN[bh][k][v] (bf16)
__global__ void ctx_reduce(const float* __restrict__ cp, const float* __restrict__ S,
                           unsigned short* __restrict__ ctxN) {
  const int bh = blockIdx.x, t = threadIdx.x;
  const float* p = cp + (size_t)bh * 4 * 4096;
  for (int i = 0; i < 16; ++i) {
    int e = i * 256 + t;
    float vsum = p[e] + p[4096 + e] + p[8192 + e] + p[12288 + e];
    int v = e >> 6, k = e & 63;
    ctxN[(size_t)bh * 4096 + k * 64 + v] = f2bf(vsum / S[bh * 64 + k]);
  }
}

// ---------------------------------------------------------------------------
// M[b][c][h*64+k] = sum_v ctxN[b,h][k][v] * Wr[h*64+v][c]   (transposed for final GEMM)
__global__ void ctx_mm(const unsigned short* __restrict__ ctxN, const unsigned short* __restrict__ Wrt,
                       unsigned short* __restrict__ MT) {
  const int t = threadIdx.x, l = t & 63, w = t >> 6;
  const int lr = l & 15, lg = l >> 4;
  const int h = blockIdx.x, b = blockIdx.y;
  const unsigned short* Ap = ctxN + (size_t)(b * 8 + h) * 4096;
  f32x4 acc[4][8] = {};
  const int c0 = w * 128;
#pragma unroll
  for (int kk = 0; kk < 2; ++kk) {
    const int vb = kk * 32 + lg * 8;
    short8 a[4], bfr[8];
#pragma unroll
    for (int m = 0; m < 4; ++m) a[m] = *(const short8*)&Ap[(m * 16 + lr) * 64 + vb];
#pragma unroll
    for (int n = 0; n < 8; ++n) bfr[n] = *(const short8*)&Wrt[(size_t)(c0 + n * 16 + lr) * 512 + h * 64 + vb];
#pragma unroll
    for (int m = 0; m < 4; ++m)
#pragma unroll
      for (int n = 0; n < 8; ++n)
        acc[m][n] = __builtin_amdgcn_mfma_f32_16x16x32_bf16(a[m], bfr[n], acc[m][n], 0, 0, 0);
  }
#pragma unroll
  for (int n = 0; n < 8; ++n) {
    const int c = c0 + n * 16 + lr;
#pragma unroll
    for (int m = 0; m < 4; ++m) {
      const int k = m * 16 + lg * 4;
      us4 v;
#pragma unroll
      for (int j = 0; j < 4; ++j) v[j] = f2bf(acc[m][n][j]);
      *(us4*)&MT[((size_t)b * 512 + c) * 512 + h * 64 + k] = v;
    }
  }
}

// ---------------------------------------------------------------------------
// Final GEMM, prefetch-pipelined, both operands bf16 via global_load_lds:
// out[tok][c] = sum_j Qs[tok][j] * MT[b][c][j] + br[c]   (fp32 out)
__global__ __launch_bounds__(256) void gemm_final(const unsigned short* __restrict__ Qs,
                           const unsigned short* __restrict__ MT,
                           const float* __restrict__ br, float* __restrict__ out) {
  __shared__ __align__(16) unsigned short As[2][128][64];
  __shared__ __align__(16) unsigned short Bs[2][128][64];
  const int t = threadIdx.x, l = t & 63, w = t >> 6;
  const int lr = l & 15, lg = l >> 4;
  const int wr = w >> 1, wc = w & 1;
  const int bid = blockIdx.x;
  const int swz = (bid & 7) * 128 + (bid >> 3);
  const int tn = swz & 3, tm = swz >> 2;   // XCD x owns batch x exactly

  const unsigned short* Ag =
      Qs + (size_t)(tm * 128 + w * 32 + (l >> 3)) * 512 + ((l & 7) ^ (l >> 3)) * 8;
  const unsigned short* Bg = MT + (size_t)(tm >> 5) * 512 * 512 +
      (size_t)(tn * 128 + w * 32 + (l >> 3)) * 512 + ((l & 7) ^ (l >> 3)) * 8;

  f32x4 acc[4][4] = {};
#pragma unroll
  for (int i = 0; i < 4; ++i) {
    gload16(Ag + (size_t)i * 8 * 512, &As[0][w * 32 + i * 8][0]);
    gload16(Bg + (size_t)i * 8 * 512, &Bs[0][w * 32 + i * 8][0]);
  }
  __syncthreads();

#pragma unroll 2
  for (int kt = 0; kt < 8; ++kt) {
    const int cur = kt & 1, nxt = cur ^ 1;
    int ktn = kt + 1; if (ktn > 7) ktn = 7;
#pragma unroll
    for (int i = 0; i < 4; ++i) {
      gload16(Ag + (size_t)i * 8 * 512 + ktn * 64, &As[nxt][w * 32 + i * 8][0]);
      gload16(Bg + (size_t)i * 8 * 512 + ktn * 64, &Bs[nxt][w * 32 + i * 8][0]);
    }
#pragma unroll
    for (int kk = 0; kk < 2; ++kk) {
      short8 af[4], bf[4];
#pragma unroll
      for (int m = 0; m < 4; ++m) {
        const int row = wr * 64 + m * 16 + lr;
        af[m] = *(const short8*)&As[cur][row][(((kk * 4 + lg) ^ (row & 7)) * 8)];
      }
#pragma unroll
      for (int n = 0; n < 4; ++n) {
        const int row = wc * 64 + n * 16 + lr;
        bf[n] = *(const short8*)&Bs[cur][row][(((kk * 4 + lg) ^ (row & 7)) * 8)];
      }
#pragma unroll
      for (int m = 0; m < 4; ++m)
#pragma unroll
        for (int n = 0; n < 4; ++n)
          acc[m][n] = __builtin_amdgcn_mfma_f32_16x16x32_bf16(af[m], bf[n], acc[m][n], 0, 0, 0);
    }
    __syncthreads();
  }

  const int c_base = tn * 128 + wc * 64;
  const int r_base = tm * 128 + wr * 64;
#pragma unroll
  for (int n = 0; n < 4; ++n) {
    const int col = c_base + n * 16 + lr;
    const float bs = br[col];
#pragma unroll
    for (int m = 0; m < 4; ++m) {
      const int row = r_base + m * 16 + lg * 4;
#pragma unroll
      for (int j = 0; j < 4; ++j)
        out[(size_t)(row + j) * 512 + col] = acc[m][n][j] + bs;
    }
  }
}

// ---------------------------------------------------------------------------
extern "C" void kernel_launch(void* const* d_in, const int* in_sizes, int n_in,
                              void* d_out, int out_size, void* d_ws, size_t ws_size,
                              hipStream_t stream) {
  (void)in_sizes; (void)n_in; (void)out_size; (void)ws_size;
  const float* x  = (const float*)d_in[0];
  const float* y  = (const float*)d_in[1];
  const float* Wk = (const float*)d_in[2];
  const float* bk = (const float*)d_in[3];
  const float* Wq = (const float*)d_in[4];
  const float* bq = (const float*)d_in[5];
  const float* Wv = (const float*)d_in[6];
  const float* bv = (const float*)d_in[7];
  const float* Wr = (const float*)d_in[8];
  const float* br = (const float*)d_in[9];
  float* out = (float*)d_out;

  char* ws = (char*)d_ws;
  unsigned short* Wt   = (unsigned short*)(ws + 0);            //  2 MB: 4x [512][512] bf16
  unsigned short* KeT  = (unsigned short*)(ws + 2097152);      // 32 MB: [B][512][4096] bf16
  unsigned short* VT   = (unsigned short*)(ws + 35651584);     // 32 MB: [B][512][4096] bf16
  unsigned short* Qp   = (unsigned short*)(ws + 69206016);     // 32 MB: [32768][512] bf16 (softmaxed)
  float* S             = (float*)(ws + 102760448);             // 16 KB
  float* cp            = (float*)(ws + 102776832);             //  4 MB
  unsigned short* ctxN = (unsigned short*)(ws + 106971136);    // .5 MB
  unsigned short* MT   = (unsigned short*)(ws + 107495424);    //  4 MB

  prep_w<<<dim3(8, 8, 4), 256, 0, stream>>>(Wk, Wq, Wv, Wr, Wt);
  gemm_proj<0><<<1024, 256, 0, stream>>>(x, y, Wt, bk, KeT);
  ssum<<<4096, 256, 0, stream>>>(KeT, S);
  gemm_proj<2><<<1024, 256, 0, stream>>>(x, nullptr, Wt + 2 * 262144, bv, VT);
  gemm_proj<1><<<1024, 256, 0, stream>>>(y, nullptr, Wt + 262144, bq, Qp);
  context_partial<<<dim3(4, 8, 8), 256, 0, stream>>>(KeT, VT, cp);
  ctx_reduce<<<64, 256, 0, stream>>>(cp, S, ctxN);
  ctx_mm<<<dim3(8, 8), 256, 0, stream>>>(ctxN, Wt + 3 * 262144, MT);
  gemm_final<<<1024, 256, 0, stream>>>(Qp, MT, br, out);
}

// Round 4
// 234.572 us; speedup vs baseline: 2.2008x; 1.3127x over previous
//
#include <hip/hip_runtime.h>
#include <hip/hip_bf16.h>
#include <stdint.h>

// Problem constants: B=8, N=4096, C=512, K=V=512, H=8, hk=hv=64, M = B*N = 32768

typedef __attribute__((ext_vector_type(8))) short short8;
typedef __attribute__((ext_vector_type(4))) float f32x4;
typedef __attribute__((ext_vector_type(4))) unsigned short us4;

__device__ __forceinline__ unsigned short f2bf(float f) {
  union { float f; unsigned u; } v; v.f = f;
  unsigned r = v.u + 0x7FFFu + ((v.u >> 16) & 1u);  // RNE
  return (unsigned short)(r >> 16);
}
__device__ __forceinline__ float bf2f(unsigned short u) {
  union { unsigned u; float f; } v; v.u = ((unsigned)u) << 16;
  return v.f;
}
__device__ __forceinline__ ushort2 pk2(float a, float b) {
  __hip_bfloat162 h = __float22bfloat162_rn(float2{a, b});
  return *reinterpret_cast<ushort2*>(&h);
}
// async global->LDS, 16B per lane; lds base wave-uniform (HW: base + lane*16)
__device__ __forceinline__ void gload16(const void* g, void* l) {
  __builtin_amdgcn_global_load_lds(
      (const __attribute__((address_space(1))) void*)g,
      (__attribute__((address_space(3))) void*)l, 16, 0, 0);
}

// ---------------------------------------------------------------------------
// Transpose + bf16-convert the 4 weight matrices: Wt[w][out][in] = W[in][out]
__global__ void prep_w(const float* __restrict__ Wk, const float* __restrict__ Wq,
                       const float* __restrict__ Wv, const float* __restrict__ Wr,
                       unsigned short* __restrict__ Wt) {
  __shared__ float tile[64][65];
  const int t = threadIdx.x;
  const int bx = blockIdx.x, by = blockIdx.y, w = blockIdx.z;
  const float* W = (w == 0) ? Wk : (w == 1) ? Wq : (w == 2) ? Wv : Wr;
  unsigned short* O = Wt + (size_t)w * 512 * 512;
#pragma unroll
  for (int p = 0; p < 16; ++p) {
    int idx = p * 256 + t; int r = idx >> 6, c = idx & 63;
    tile[r][c] = W[(size_t)(by * 64 + r) * 512 + bx * 64 + c];
  }
  __syncthreads();
#pragma unroll
  for (int p = 0; p < 16; ++p) {
    int idx = p * 256 + t; int r = idx >> 6, c = idx & 63;
    O[(size_t)(bx * 64 + r) * 512 + by * 64 + c] = f2bf(tile[c][r]);
  }
}

// ---------------------------------------------------------------------------
// Streaming pre-pass: xb=bf16(x), yb=bf16(y), xyb=bf16(x+y). 8 elems/thread.
__global__ __launch_bounds__(256) void prep_xy(const float* __restrict__ x, const float* __restrict__ y,
                        unsigned short* __restrict__ xb, unsigned short* __restrict__ yb,
                        unsigned short* __restrict__ xyb) {
  const size_t i = ((size_t)blockIdx.x * 256 + threadIdx.x) * 8;
  float4 a0 = *(const float4*)(x + i), a1 = *(const float4*)(x + i + 4);
  float4 b0 = *(const float4*)(y + i), b1 = *(const float4*)(y + i + 4);
  short8 vx, vy, vs;
  ushort2 p;
  p = pk2(a0.x, a0.y); vx[0] = (short)p.x; vx[1] = (short)p.y;
  p = pk2(a0.z, a0.w); vx[2] = (short)p.x; vx[3] = (short)p.y;
  p = pk2(a1.x, a1.y); vx[4] = (short)p.x; vx[5] = (short)p.y;
  p = pk2(a1.z, a1.w); vx[6] = (short)p.x; vx[7] = (short)p.y;
  p = pk2(b0.x, b0.y); vy[0] = (short)p.x; vy[1] = (short)p.y;
  p = pk2(b0.z, b0.w); vy[2] = (short)p.x; vy[3] = (short)p.y;
  p = pk2(b1.x, b1.y); vy[4] = (short)p.x; vy[5] = (short)p.y;
  p = pk2(b1.z, b1.w); vy[6] = (short)p.x; vy[7] = (short)p.y;
  p = pk2(a0.x + b0.x, a0.y + b0.y); vs[0] = (short)p.x; vs[1] = (short)p.y;
  p = pk2(a0.z + b0.z, a0.w + b0.w); vs[2] = (short)p.x; vs[3] = (short)p.y;
  p = pk2(a1.x + b1.x, a1.y + b1.y); vs[4] = (short)p.x; vs[5] = (short)p.y;
  p = pk2(a1.z + b1.z, a1.w + b1.w); vs[6] = (short)p.x; vs[7] = (short)p.y;
  *(short8*)(xb + i) = vx;
  *(short8*)(yb + i) = vy;
  *(short8*)(xyb + i) = vs;
}

// ---------------------------------------------------------------------------
// m97-clone bf16 GEMM: C[128x128 tile] = A[M][512] @ B[N][512]^T (+bias).
// global_load_lds(16B) both operands, linear LDS, single-buffered 2-barrier loop.
// MODE 0: epilogue exp(), TRANSPOSED out (KeT[b][k][tok], bf16)
// MODE 1: epilogue fused head-softmax (64 ch), row-major bf16 out
// MODE 2: plain, TRANSPOSED out (VT[b][v][tok], bf16)
// MODE 3: final: B = MT + batch*512*512, fp32 row-major out + bias
template <int MODE>
__global__ __launch_bounds__(256) void gemm_bf16(const unsigned short* __restrict__ A,
                          const unsigned short* __restrict__ Bmat,
                          const float* __restrict__ bias, void* __restrict__ OutV) {
  __shared__ __align__(16) unsigned short As[128][64];
  __shared__ __align__(16) unsigned short Bs[128][64];
  const int t = threadIdx.x, l = t & 63, w = t >> 6;
  const int lr = l & 15, lg = l >> 4;
  const int wr = w >> 1, wc = w & 1;
  const int bid = blockIdx.x;
  const int swz = (bid & 7) * 128 + (bid >> 3);  // bijective XCD swizzle (1024 % 8 == 0)
  const int tn = swz & 3, tm = swz >> 2;

  const unsigned short* Bbase = (MODE == 3) ? (Bmat + (size_t)(tm >> 5) * 262144) : Bmat;
  const int r0 = w * 8 + (l >> 3);   // staging row within a 32-row chunk
  const int c8 = (l & 7) * 8;        // staging col (shorts)
  const unsigned short* Ag = A + (size_t)(tm * 128 + r0) * 512 + c8;
  const unsigned short* Bg = Bbase + (size_t)(tn * 128 + r0) * 512 + c8;

  f32x4 acc[4][4] = {};
  for (int kt = 0; kt < 8; ++kt) {
    // ---- stage tile kt (DMA, linear LDS) ----
#pragma unroll
    for (int i = 0; i < 4; ++i) {
      gload16(Ag + (size_t)i * 32 * 512 + kt * 64, &As[i * 32 + w * 8][0]);
      gload16(Bg + (size_t)i * 32 * 512 + kt * 64, &Bs[i * 32 + w * 8][0]);
    }
    __syncthreads();  // drains vmcnt -> tile ready
    // ---- compute ----
#pragma unroll
    for (int kk = 0; kk < 2; ++kk) {
      short8 af[4], bf[4];
#pragma unroll
      for (int m = 0; m < 4; ++m) af[m] = *(const short8*)&As[wr * 64 + m * 16 + lr][kk * 32 + lg * 8];
#pragma unroll
      for (int n = 0; n < 4; ++n) bf[n] = *(const short8*)&Bs[wc * 64 + n * 16 + lr][kk * 32 + lg * 8];
#pragma unroll
      for (int m = 0; m < 4; ++m)
#pragma unroll
        for (int n = 0; n < 4; ++n)
          acc[m][n] = __builtin_amdgcn_mfma_f32_16x16x32_bf16(af[m], bf[n], acc[m][n], 0, 0, 0);
    }
    __syncthreads();  // readers done before next DMA overwrites
  }

  // ---- epilogue ----
  const int c_base = tn * 128 + wc * 64;
  const int r_base = tm * 128 + wr * 64;
  float bv_[4];
#pragma unroll
  for (int n = 0; n < 4; ++n) bv_[n] = bias[c_base + n * 16 + lr];

  if (MODE == 1) {
    unsigned short* Out = (unsigned short*)OutV;
    // fused query-softmax over this wave's 64 cols (= one head), fp32 in-register
#pragma unroll
    for (int m = 0; m < 4; ++m) {
#pragma unroll
      for (int j = 0; j < 4; ++j) {
        float a0 = acc[m][0][j] + bv_[0], a1 = acc[m][1][j] + bv_[1];
        float a2 = acc[m][2][j] + bv_[2], a3 = acc[m][3][j] + bv_[3];
        float mx = fmaxf(fmaxf(a0, a1), fmaxf(a2, a3));
#pragma unroll
        for (int o = 1; o < 16; o <<= 1) mx = fmaxf(mx, __shfl_xor(mx, o));
        float e0 = __expf(a0 - mx), e1 = __expf(a1 - mx);
        float e2 = __expf(a2 - mx), e3 = __expf(a3 - mx);
        float s = e0 + e1 + e2 + e3;
#pragma unroll
        for (int o = 1; o < 16; o <<= 1) s += __shfl_xor(s, o);
        const float rs = 1.0f / s;
        const int row = r_base + m * 16 + lg * 4 + j;
        Out[(size_t)row * 512 + c_base + 0 * 16 + lr] = f2bf(e0 * rs);
        Out[(size_t)row * 512 + c_base + 1 * 16 + lr] = f2bf(e1 * rs);
        Out[(size_t)row * 512 + c_base + 2 * 16 + lr] = f2bf(e2 * rs);
        Out[(size_t)row * 512 + c_base + 3 * 16 + lr] = f2bf(e3 * rs);
      }
    }
  } else if (MODE == 3) {
    float* Out = (float*)OutV;
#pragma unroll
    for (int n = 0; n < 4; ++n) {
      const int col = c_base + n * 16 + lr;
#pragma unroll
      for (int m = 0; m < 4; ++m) {
        const int row = r_base + m * 16 + lg * 4;
#pragma unroll
        for (int j = 0; j < 4; ++j)
          Out[(size_t)(row + j) * 512 + col] = acc[m][n][j] + bv_[n];
      }
    }
  } else {
    unsigned short* Out = (unsigned short*)OutV;
#pragma unroll
    for (int n = 0; n < 4; ++n) {
      const int col = c_base + n * 16 + lr;
#pragma unroll
      for (int m = 0; m < 4; ++m) {
        const int row = r_base + m * 16 + lg * 4;
        const int b = row >> 12, nl = row & 4095;  // tile rows never cross a batch
        us4 v;
#pragma unroll
        for (int j = 0; j < 4; ++j) {
          float f = acc[m][n][j] + bv_[n];
          if (MODE == 0) f = __expf(f);
          v[j] = f2bf(f);
        }
        *(us4*)&Out[((size_t)(b * 512 + col)) * 4096 + nl] = v;
      }
    }
  }
}

// ---------------------------------------------------------------------------
// S[b*512+k] = sum over 4096 tokens of KeT row (key-softmax denominator)
__global__ void ssum(const unsigned short* __restrict__ KeT, float* __restrict__ S) {
  const int t = threadIdx.x;
  const int row = blockIdx.x;
  const unsigned short* p = KeT + (size_t)row * 4096 + t * 16;
  float s = 0.f;
#pragma unroll
  for (int q = 0; q < 2; ++q) {
    short8 v = *(const short8*)(p + q * 8);
#pragma unroll
    for (int j = 0; j < 8; ++j) s += bf2f((unsigned short)v[j]);
  }
#pragma unroll
  for (int o = 32; o; o >>= 1) s += __shfl_xor(s, o);
  __shared__ float ls[4];
  if ((t & 63) == 0) ls[t >> 6] = s;
  __syncthreads();
  if (t == 0) S[row] = ls[0] + ls[1] + ls[2] + ls[3];
}

// ---------------------------------------------------------------------------
// Partial context: D[v][k] = sum_tok VT[v][tok] * KeT[k][tok] over a 1024-token chunk.
__global__ void context_partial(const unsigned short* __restrict__ KeT,
                                const unsigned short* __restrict__ VT,
                                float* __restrict__ cp) {
  const int t = threadIdx.x, l = t & 63, w = t >> 6;
  const int lr = l & 15, lg = l >> 4;
  const int ch = blockIdx.x, h = blockIdx.y, b = blockIdx.z;
  const unsigned short* Kp = KeT + ((size_t)b * 512 + h * 64) * 4096;
  const unsigned short* Vp = VT + ((size_t)b * 512 + h * 64) * 4096;
  const int tok_w = ch * 1024 + w * 256;
  f32x4 acc[4][4] = {};
  for (int s = 0; s < 8; ++s) {
    const int tok = tok_w + s * 32 + lg * 8;
    short8 a[4], kf[4];
#pragma unroll
    for (int m = 0; m < 4; ++m) a[m] = *(const short8*)&Vp[(size_t)(m * 16 + lr) * 4096 + tok];
#pragma unroll
    for (int n = 0; n < 4; ++n) kf[n] = *(const short8*)&Kp[(size_t)(n * 16 + lr) * 4096 + tok];
#pragma unroll
    for (int m = 0; m < 4; ++m)
#pragma unroll
      for (int n = 0; n < 4; ++n)
        acc[m][n] = __builtin_amdgcn_mfma_f32_16x16x32_bf16(a[m], kf[n], acc[m][n], 0, 0, 0);
  }
  __shared__ float red[4][64][64];
#pragma unroll
  for (int m = 0; m < 4; ++m)
#pragma unroll
    for (int n = 0; n < 4; ++n)
#pragma unroll
      for (int j = 0; j < 4; ++j)
        red[w][m * 16 + lg * 4 + j][n * 16 + lr] = acc[m][n][j];
  __syncthreads();
  const int blk = (b * 8 + h) * 4 + ch;
  float* o = cp + (size_t)blk * 4096;
  for (int i = 0; i < 16; ++i) {
    int e = i * 256 + t;
    int v = e >> 6, k = e & 63;
    o[e] = red[0][v][k] + red[1][v][k] + red[2][v][k] + red[3][v][k];
  }
}

// Reduce 4 chunk-partials, normalize by S, store transposed: ctxN[bh][k][v] (bf16)
__global__ void ctx_reduce(const float* __restrict__ cp, const float* __restrict__ S,
                           unsigned short* __restrict__ ctxN) {
  const int bh = blockIdx.x, t = threadIdx.x;
  const float* p = cp + (size_t)bh * 4 * 4096;
  for (int i = 0; i < 16; ++i) {
    int e = i * 256 + t;
    float vsum = p[e] + p[4096 + e] + p[8192 + e] + p[12288 + e];
    int v = e >> 6, k = e & 63;
    ctxN[(size_t)bh * 4096 + k * 64 + v] = f2bf(vsum / S[bh * 64 + k]);
  }
}

// ---------------------------------------------------------------------------
// M[b][c][h*64+k] = sum_v ctxN[b,h][k][v] * Wr[h*64+v][c]   (transposed for final GEMM)
__global__ void ctx_mm(const unsigned short* __restrict__ ctxN, const unsigned short* __restrict__ Wrt,
                       unsigned short* __restrict__ MT) {
  const int t = threadIdx.x, l = t & 63, w = t >> 6;
  const int lr = l & 15, lg = l >> 4;
  const int h = blockIdx.x, b = blockIdx.y;
  const unsigned short* Ap = ctxN + (size_t)(b * 8 + h) * 4096;
  f32x4 acc[4][8] = {};
  const int c0 = w * 128;
#pragma unroll
  for (int kk = 0; kk < 2; ++kk) {
    const int vb = kk * 32 + lg * 8;
    short8 a[4], bfr[8];
#pragma unroll
    for (int m = 0; m < 4; ++m) a[m] = *(const short8*)&Ap[(m * 16 + lr) * 64 + vb];
#pragma unroll
    for (int n = 0; n < 8; ++n) bfr[n] = *(const short8*)&Wrt[(size_t)(c0 + n * 16 + lr) * 512 + h * 64 + vb];
#pragma unroll
    for (int m = 0; m < 4; ++m)
#pragma unroll
      for (int n = 0; n < 8; ++n)
        acc[m][n] = __builtin_amdgcn_mfma_f32_16x16x32_bf16(a[m], bfr[n], acc[m][n], 0, 0, 0);
  }
#pragma unroll
  for (int n = 0; n < 8; ++n) {
    const int c = c0 + n * 16 + lr;
#pragma unroll
    for (int m = 0; m < 4; ++m) {
      const int k = m * 16 + lg * 4;
      us4 v;
#pragma unroll
      for (int j = 0; j < 4; ++j) v[j] = f2bf(acc[m][n][j]);
      *(us4*)&MT[((size_t)b * 512 + c) * 512 + h * 64 + k] = v;
    }
  }
}

// ---------------------------------------------------------------------------
extern "C" void kernel_launch(void* const* d_in, const int* in_sizes, int n_in,
                              void* d_out, int out_size, void* d_ws, size_t ws_size,
                              hipStream_t stream) {
  (void)in_sizes; (void)n_in; (void)out_size; (void)ws_size;
  const float* x  = (const float*)d_in[0];
  const float* y  = (const float*)d_in[1];
  const float* Wk = (const float*)d_in[2];
  const float* bk = (const float*)d_in[3];
  const float* Wq = (const float*)d_in[4];
  const float* bq = (const float*)d_in[5];
  const float* Wv = (const float*)d_in[6];
  const float* bv = (const float*)d_in[7];
  const float* Wr = (const float*)d_in[8];
  const float* br = (const float*)d_in[9];
  float* out = (float*)d_out;

  char* ws = (char*)d_ws;
  unsigned short* Wt   = (unsigned short*)(ws + 0);            //   2 MB: 4x [512][512] bf16
  unsigned short* xb   = (unsigned short*)(ws + 2097152);      //  32 MB: bf16(x)
  unsigned short* yb   = (unsigned short*)(ws + 35651584);     //  32 MB: bf16(y)
  unsigned short* xyb  = (unsigned short*)(ws + 69206016);     //  32 MB: bf16(x+y); reused as Qp after g0
  unsigned short* KeT  = (unsigned short*)(ws + 102760448);    //  32 MB: [B][512][4096] bf16
  unsigned short* VT   = (unsigned short*)(ws + 136314880);    //  32 MB: [B][512][4096] bf16
  float* S             = (float*)(ws + 169869312);             //  16 KB
  float* cp            = (float*)(ws + 169885696);             //   4 MB
  unsigned short* ctxN = (unsigned short*)(ws + 174080000);    //  .5 MB
  unsigned short* MT   = (unsigned short*)(ws + 174604288);    //   4 MB  (end ~179 MB)
  unsigned short* Qp   = xyb;                                  // xyb dead after gemm<0>

  prep_w<<<dim3(8, 8, 4), 256, 0, stream>>>(Wk, Wq, Wv, Wr, Wt);
  prep_xy<<<8192, 256, 0, stream>>>(x, y, xb, yb, xyb);
  gemm_bf16<0><<<1024, 256, 0, stream>>>(xyb, Wt, bk, KeT);
  ssum<<<4096, 256, 0, stream>>>(KeT, S);
  gemm_bf16<2><<<1024, 256, 0, stream>>>(xb, Wt + 2 * 262144, bv, VT);
  gemm_bf16<1><<<1024, 256, 0, stream>>>(yb, Wt + 262144, bq, Qp);
  context_partial<<<dim3(4, 8, 8), 256, 0, stream>>>(KeT, VT, cp);
  ctx_reduce<<<64, 256, 0, stream>>>(cp, S, ctxN);
  ctx_mm<<<dim3(8, 8), 256, 0, stream>>>(ctxN, Wt + 3 * 262144, MT);
  gemm_bf16<3><<<1024, 256, 0, stream>>>(Qp, MT, br, out);
}

// Round 5
// 214.800 us; speedup vs baseline: 2.4034x; 1.0920x over previous
//
#include <hip/hip_runtime.h>
#include <hip/hip_bf16.h>
#include <stdint.h>

// Problem constants: B=8, N=4096, C=512, K=V=512, H=8, hk=hv=64, M = B*N = 32768

typedef __attribute__((ext_vector_type(8))) short short8;
typedef __attribute__((ext_vector_type(4))) float f32x4;
typedef __attribute__((ext_vector_type(4))) unsigned short us4;

__device__ __forceinline__ unsigned short f2bf(float f) {
  union { float f; unsigned u; } v; v.f = f;
  unsigned r = v.u + 0x7FFFu + ((v.u >> 16) & 1u);  // RNE
  return (unsigned short)(r >> 16);
}
__device__ __forceinline__ float bf2f(unsigned short u) {
  union { unsigned u; float f; } v; v.u = ((unsigned)u) << 16;
  return v.f;
}
__device__ __forceinline__ ushort2 pk2(float a, float b) {
  __hip_bfloat162 h = __float22bfloat162_rn(float2{a, b});
  return *reinterpret_cast<ushort2*>(&h);
}
// async global->LDS, 16B per lane; lds base wave-uniform (HW: base + lane*16)
__device__ __forceinline__ void gload16(const void* g, void* l) {
  __builtin_amdgcn_global_load_lds(
      (const __attribute__((address_space(1))) void*)g,
      (__attribute__((address_space(3))) void*)l, 16, 0, 0);
}

// ---------------------------------------------------------------------------
// Transpose + bf16-convert the 4 weight matrices: Wt[w][out][in] = W[in][out]
__global__ void prep_w(const float* __restrict__ Wk, const float* __restrict__ Wq,
                       const float* __restrict__ Wv, const float* __restrict__ Wr,
                       unsigned short* __restrict__ Wt) {
  __shared__ float tile[64][65];
  const int t = threadIdx.x;
  const int bx = blockIdx.x, by = blockIdx.y, w = blockIdx.z;
  const float* W = (w == 0) ? Wk : (w == 1) ? Wq : (w == 2) ? Wv : Wr;
  unsigned short* O = Wt + (size_t)w * 512 * 512;
#pragma unroll
  for (int p = 0; p < 16; ++p) {
    int idx = p * 256 + t; int r = idx >> 6, c = idx & 63;
    tile[r][c] = W[(size_t)(by * 64 + r) * 512 + bx * 64 + c];
  }
  __syncthreads();
#pragma unroll
  for (int p = 0; p < 16; ++p) {
    int idx = p * 256 + t; int r = idx >> 6, c = idx & 63;
    O[(size_t)(bx * 64 + r) * 512 + by * 64 + c] = f2bf(tile[c][r]);
  }
}

// ---------------------------------------------------------------------------
// Streaming pre-pass: xb=bf16(x), yb=bf16(y), xyb=bf16(x+y). Grid-stride,
// 16 elems/thread/iter for load ILP.
__global__ __launch_bounds__(256) void prep_xy(const float* __restrict__ x, const float* __restrict__ y,
                        unsigned short* __restrict__ xb, unsigned short* __restrict__ yb,
                        unsigned short* __restrict__ xyb) {
  const size_t total = (size_t)8 * 4096 * 512;          // 16.7M
  const size_t stride = (size_t)gridDim.x * 256 * 16;
  for (size_t i0 = ((size_t)blockIdx.x * 256 + threadIdx.x) * 16; i0 < total; i0 += stride) {
    float4 a[4], b[4];
#pragma unroll
    for (int q = 0; q < 4; ++q) { a[q] = *(const float4*)(x + i0 + q * 4); }
#pragma unroll
    for (int q = 0; q < 4; ++q) { b[q] = *(const float4*)(y + i0 + q * 4); }
#pragma unroll
    for (int h = 0; h < 2; ++h) {
      float4 a0 = a[2 * h], a1 = a[2 * h + 1], b0 = b[2 * h], b1 = b[2 * h + 1];
      short8 vx, vy, vs;
      ushort2 p;
      p = pk2(a0.x, a0.y); vx[0] = (short)p.x; vx[1] = (short)p.y;
      p = pk2(a0.z, a0.w); vx[2] = (short)p.x; vx[3] = (short)p.y;
      p = pk2(a1.x, a1.y); vx[4] = (short)p.x; vx[5] = (short)p.y;
      p = pk2(a1.z, a1.w); vx[6] = (short)p.x; vx[7] = (short)p.y;
      p = pk2(b0.x, b0.y); vy[0] = (short)p.x; vy[1] = (short)p.y;
      p = pk2(b0.z, b0.w); vy[2] = (short)p.x; vy[3] = (short)p.y;
      p = pk2(b1.x, b1.y); vy[4] = (short)p.x; vy[5] = (short)p.y;
      p = pk2(b1.z, b1.w); vy[6] = (short)p.x; vy[7] = (short)p.y;
      p = pk2(a0.x + b0.x, a0.y + b0.y); vs[0] = (short)p.x; vs[1] = (short)p.y;
      p = pk2(a0.z + b0.z, a0.w + b0.w); vs[2] = (short)p.x; vs[3] = (short)p.y;
      p = pk2(a1.x + b1.x, a1.y + b1.y); vs[4] = (short)p.x; vs[5] = (short)p.y;
      p = pk2(a1.z + b1.z, a1.w + b1.w); vs[6] = (short)p.x; vs[7] = (short)p.y;
      *(short8*)(xb + i0 + h * 8) = vx;
      *(short8*)(yb + i0 + h * 8) = vy;
      *(short8*)(xyb + i0 + h * 8) = vs;
    }
  }
}

// ---------------------------------------------------------------------------
// bf16 GEMM, T2+T4: 128x128 tile, BK=64, double-buffered LDS (64KB),
// counted vmcnt (never 0 mid-loop), raw s_barrier, XOR-swizzled LDS
// (linear gload dest + pre-swizzled global src, swizzled ds_read).
// MODE 0: epilogue exp(), TRANSPOSED out (KeT[b][k][tok], bf16)
// MODE 1: epilogue fused head-softmax (64 ch), row-major bf16 out
// MODE 2: plain, TRANSPOSED out (VT[b][v][tok], bf16)
// MODE 3: final: B = MT + batch*512*512, fp32 row-major out + bias
template <int MODE>
__global__ __launch_bounds__(256) void gemm_bf16(const unsigned short* __restrict__ A,
                          const unsigned short* __restrict__ Bmat,
                          const float* __restrict__ bias, void* __restrict__ OutV) {
  __shared__ __align__(16) unsigned short As[2][128][64];
  __shared__ __align__(16) unsigned short Bs[2][128][64];
  const int t = threadIdx.x, l = t & 63, w = t >> 6;
  const int lr = l & 15, lg = l >> 4;
  const int wr = w >> 1, wc = w & 1;
  const int bid = blockIdx.x;
  const int swz = (bid & 7) * 128 + (bid >> 3);  // bijective XCD swizzle (1024 % 8 == 0)
  const int tn = swz & 3, tm = swz >> 2;

  const unsigned short* Bbase = (MODE == 3) ? (Bmat + (size_t)(tm >> 5) * 262144) : Bmat;
  // staging: lane l covers LDS row (l>>3), phys 16B-unit (l&7). Pre-swizzle the
  // GLOBAL source so phys unit p holds logical unit p^(row&7)  [G21]
  const int r0 = w * 8 + (l >> 3);
  const int su = ((l & 7) ^ (l >> 3)) * 8;       // logical source col (shorts)
  const unsigned short* Ag = A + (size_t)(tm * 128 + r0) * 512 + su;
  const unsigned short* Bg = Bbase + (size_t)(tn * 128 + r0) * 512 + su;

  f32x4 acc[4][4] = {};

#define PSTAGE(buf, kt)                                                        \
  {                                                                            \
    _Pragma("unroll") for (int i = 0; i < 4; ++i) {                            \
      gload16(Ag + (size_t)i * 32 * 512 + (kt) * 64, &As[buf][i * 32 + w * 8][0]); \
      gload16(Bg + (size_t)i * 32 * 512 + (kt) * 64, &Bs[buf][i * 32 + w * 8][0]); \
    }                                                                          \
  }

  PSTAGE(0, 0)
  PSTAGE(1, 1)
  for (int kt = 0; kt < 8; ++kt) {
    const int cur = kt & 1;
    // wait for tile kt only (8 loads of tile kt+1 may stay in flight)  [T4]
    if (kt < 7) { asm volatile("s_waitcnt vmcnt(8)" ::: "memory"); }
    else        { asm volatile("s_waitcnt vmcnt(0)" ::: "memory"); }
    __builtin_amdgcn_s_barrier();
    asm volatile("" ::: "memory");   // keep ds_reads below the barrier
    __builtin_amdgcn_s_setprio(1);
#pragma unroll
    for (int kk = 0; kk < 2; ++kk) {
      short8 af[4], bf[4];
#pragma unroll
      for (int m = 0; m < 4; ++m)
        af[m] = *(const short8*)&As[cur][wr * 64 + m * 16 + lr][((kk * 4 + lg) ^ (lr & 7)) * 8];
#pragma unroll
      for (int n = 0; n < 4; ++n)
        bf[n] = *(const short8*)&Bs[cur][wc * 64 + n * 16 + lr][((kk * 4 + lg) ^ (lr & 7)) * 8];
#pragma unroll
      for (int m = 0; m < 4; ++m)
#pragma unroll
        for (int n = 0; n < 4; ++n)
          acc[m][n] = __builtin_amdgcn_mfma_f32_16x16x32_bf16(af[m], bf[n], acc[m][n], 0, 0, 0);
    }
    __builtin_amdgcn_s_setprio(0);
    asm volatile("" ::: "memory");
    __builtin_amdgcn_s_barrier();    // all waves done reading buf[cur]
    asm volatile("" ::: "memory");
    if (kt < 6) PSTAGE(cur, kt + 2)  // overwrite released buffer
  }
#undef PSTAGE

  // ---- epilogue ----
  const int c_base = tn * 128 + wc * 64;
  const int r_base = tm * 128 + wr * 64;
  float bv_[4];
#pragma unroll
  for (int n = 0; n < 4; ++n) bv_[n] = bias[c_base + n * 16 + lr];

  if (MODE == 1) {
    unsigned short* Out = (unsigned short*)OutV;
    // fused query-softmax over this wave's 64 cols (= one head), fp32 in-register
#pragma unroll
    for (int m = 0; m < 4; ++m) {
#pragma unroll
      for (int j = 0; j < 4; ++j) {
        float a0 = acc[m][0][j] + bv_[0], a1 = acc[m][1][j] + bv_[1];
        float a2 = acc[m][2][j] + bv_[2], a3 = acc[m][3][j] + bv_[3];
        float mx = fmaxf(fmaxf(a0, a1), fmaxf(a2, a3));
#pragma unroll
        for (int o = 1; o < 16; o <<= 1) mx = fmaxf(mx, __shfl_xor(mx, o));
        float e0 = __expf(a0 - mx), e1 = __expf(a1 - mx);
        float e2 = __expf(a2 - mx), e3 = __expf(a3 - mx);
        float s = e0 + e1 + e2 + e3;
#pragma unroll
        for (int o = 1; o < 16; o <<= 1) s += __shfl_xor(s, o);
        const float rs = 1.0f / s;
        const int row = r_base + m * 16 + lg * 4 + j;
        Out[(size_t)row * 512 + c_base + 0 * 16 + lr] = f2bf(e0 * rs);
        Out[(size_t)row * 512 + c_base + 1 * 16 + lr] = f2bf(e1 * rs);
        Out[(size_t)row * 512 + c_base + 2 * 16 + lr] = f2bf(e2 * rs);
        Out[(size_t)row * 512 + c_base + 3 * 16 + lr] = f2bf(e3 * rs);
      }
    }
  } else if (MODE == 3) {
    float* Out = (float*)OutV;
#pragma unroll
    for (int n = 0; n < 4; ++n) {
      const int col = c_base + n * 16 + lr;
#pragma unroll
      for (int m = 0; m < 4; ++m) {
        const int row = r_base + m * 16 + lg * 4;
#pragma unroll
        for (int j = 0; j < 4; ++j)
          Out[(size_t)(row + j) * 512 + col] = acc[m][n][j] + bv_[n];
      }
    }
  } else {
    unsigned short* Out = (unsigned short*)OutV;
#pragma unroll
    for (int n = 0; n < 4; ++n) {
      const int col = c_base + n * 16 + lr;
#pragma unroll
      for (int m = 0; m < 4; ++m) {
        const int row = r_base + m * 16 + lg * 4;
        const int b = row >> 12, nl = row & 4095;  // tile rows never cross a batch
        us4 v;
#pragma unroll
        for (int j = 0; j < 4; ++j) {
          float f = acc[m][n][j] + bv_[n];
          if (MODE == 0) f = __expf(f);
          v[j] = f2bf(f);
        }
        *(us4*)&Out[((size_t)(b * 512 + col)) * 4096 + nl] = v;
      }
    }
  }
}

// ---------------------------------------------------------------------------
// S[b*512+k] = sum over 4096 tokens of KeT row (key-softmax denominator)
__global__ void ssum(const unsigned short* __restrict__ KeT, float* __restrict__ S) {
  const int t = threadIdx.x;
  const int row = blockIdx.x;
  const unsigned short* p = KeT + (size_t)row * 4096 + t * 16;
  float s = 0.f;
#pragma unroll
  for (int q = 0; q < 2; ++q) {
    short8 v = *(const short8*)(p + q * 8);
#pragma unroll
    for (int j = 0; j < 8; ++j) s += bf2f((unsigned short)v[j]);
  }
#pragma unroll
  for (int o = 32; o; o >>= 1) s += __shfl_xor(s, o);
  __shared__ float ls[4];
  if ((t & 63) == 0) ls[t >> 6] = s;
  __syncthreads();
  if (t == 0) S[row] = ls[0] + ls[1] + ls[2] + ls[3];
}

// ---------------------------------------------------------------------------
// Partial context: D[v][k] = sum_tok VT[v][tok] * KeT[k][tok] over a 1024-token chunk.
__global__ void context_partial(const unsigned short* __restrict__ KeT,
                                const unsigned short* __restrict__ VT,
                                float* __restrict__ cp) {
  const int t = threadIdx.x, l = t & 63, w = t >> 6;
  const int lr = l & 15, lg = l >> 4;
  const int ch = blockIdx.x, h = blockIdx.y, b = blockIdx.z;
  const unsigned short* Kp = KeT + ((size_t)b * 512 + h * 64) * 4096;
  const unsigned short* Vp = VT + ((size_t)b * 512 + h * 64) * 4096;
  const int tok_w = ch * 1024 + w * 256;
  f32x4 acc[4][4] = {};
  for (int s = 0; s < 8; ++s) {
    const int tok = tok_w + s * 32 + lg * 8;
    short8 a[4], kf[4];
#pragma unroll
    for (int m = 0; m < 4; ++m) a[m] = *(const short8*)&Vp[(size_t)(m * 16 + lr) * 4096 + tok];
#pragma unroll
    for (int n = 0; n < 4; ++n) kf[n] = *(const short8*)&Kp[(size_t)(n * 16 + lr) * 4096 + tok];
#pragma unroll
    for (int m = 0; m < 4; ++m)
#pragma unroll
      for (int n = 0; n < 4; ++n)
        acc[m][n] = __builtin_amdgcn_mfma_f32_16x16x32_bf16(a[m], kf[n], acc[m][n], 0, 0, 0);
  }
  __shared__ float red[4][64][64];
#pragma unroll
  for (int m = 0; m < 4; ++m)
#pragma unroll
    for (int n = 0; n < 4; ++n)
#pragma unroll
      for (int j = 0; j < 4; ++j)
        red[w][m * 16 + lg * 4 + j][n * 16 + lr] = acc[m][n][j];
  __syncthreads();
  const int blk = (b * 8 + h) * 4 + ch;
  float* o = cp + (size_t)blk * 4096;
  for (int i = 0; i < 16; ++i) {
    int e = i * 256 + t;
    int v = e >> 6, k = e & 63;
    o[e] = red[0][v][k] + red[1][v][k] + red[2][v][k] + red[3][v][k];
  }
}

// Reduce 4 chunk-partials, normalize by S, store transposed: ctxN[bh][k][v] (bf16)
__global__ void ctx_reduce(const float* __restrict__ cp, const float* __restrict__ S,
                           unsigned short* __restrict__ ctxN) {
  const int bh = blockIdx.x, t = threadIdx.x;
  const float* p = cp + (size_t)bh * 4 * 4096;
  for (int i = 0; i < 16; ++i) {
    int e = i * 256 + t;
    float vsum = p[e] + p[4096 + e] + p[8192 + e] + p[12288 + e];
    int v = e >> 6, k = e & 63;
    ctxN[(size_t)bh * 4096 + k * 64 + v] = f2bf(vsum / S[bh * 64 + k]);
  }
}

// ---------------------------------------------------------------------------
// M[b][c][h*64+k] = sum_v ctxN[b,h][k][v] * Wr[h*64+v][c]   (transposed for final GEMM)
__global__ void ctx_mm(const unsigned short* __restrict__ ctxN, const unsigned short* __restrict__ Wrt,
                       unsigned short* __restrict__ MT) {
  const int t = threadIdx.x, l = t & 63, w = t >> 6;
  const int lr = l & 15, lg = l >> 4;
  const int h = blockIdx.x, b = blockIdx.y;
  const unsigned short* Ap = ctxN + (size_t)(b * 8 + h) * 4096;
  f32x4 acc[4][8] = {};
  const int c0 = w * 128;
#pragma unroll
  for (int kk = 0; kk < 2; ++kk) {
    const int vb = kk * 32 + lg * 8;
    short8 a[4], bfr[8];
#pragma unroll
    for (int m = 0; m < 4; ++m) a[m] = *(const short8*)&Ap[(m * 16 + lr) * 64 + vb];
#pragma unroll
    for (int n = 0; n < 8; ++n) bfr[n] = *(const short8*)&Wrt[(size_t)(c0 + n * 16 + lr) * 512 + h * 64 + vb];
#pragma unroll
    for (int m = 0; m < 4; ++m)
#pragma unroll
      for (int n = 0; n < 8; ++n)
        acc[m][n] = __builtin_amdgcn_mfma_f32_16x16x32_bf16(a[m], bfr[n], acc[m][n], 0, 0, 0);
  }
#pragma unroll
  for (int n = 0; n < 8; ++n) {
    const int c = c0 + n * 16 + lr;
#pragma unroll
    for (int m = 0; m < 4; ++m) {
      const int k = m * 16 + lg * 4;
      us4 v;
#pragma unroll
      for (int j = 0; j < 4; ++j) v[j] = f2bf(acc[m][n][j]);
      *(us4*)&MT[((size_t)b * 512 + c) * 512 + h * 64 + k] = v;
    }
  }
}

// ---------------------------------------------------------------------------
extern "C" void kernel_launch(void* const* d_in, const int* in_sizes, int n_in,
                              void* d_out, int out_size, void* d_ws, size_t ws_size,
                              hipStream_t stream) {
  (void)in_sizes; (void)n_in; (void)out_size; (void)ws_size;
  const float* x  = (const float*)d_in[0];
  const float* y  = (const float*)d_in[1];
  const float* Wk = (const float*)d_in[2];
  const float* bk = (const float*)d_in[3];
  const float* Wq = (const float*)d_in[4];
  const float* bq = (const float*)d_in[5];
  const float* Wv = (const float*)d_in[6];
  const float* bv = (const float*)d_in[7];
  const float* Wr = (const float*)d_in[8];
  const float* br = (const float*)d_in[9];
  float* out = (float*)d_out;

  char* ws = (char*)d_ws;
  unsigned short* Wt   = (unsigned short*)(ws + 0);            //   2 MB: 4x [512][512] bf16
  unsigned short* xb   = (unsigned short*)(ws + 2097152);      //  32 MB: bf16(x)
  unsigned short* yb   = (unsigned short*)(ws + 35651584);     //  32 MB: bf16(y)
  unsigned short* xyb  = (unsigned short*)(ws + 69206016);     //  32 MB: bf16(x+y); reused as Qp after g0
  unsigned short* KeT  = (unsigned short*)(ws + 102760448);    //  32 MB: [B][512][4096] bf16
  unsigned short* VT   = (unsigned short*)(ws + 136314880);    //  32 MB: [B][512][4096] bf16
  float* S             = (float*)(ws + 169869312);             //  16 KB
  float* cp            = (float*)(ws + 169885696);             //   4 MB
  unsigned short* ctxN = (unsigned short*)(ws + 174080000);    //  .5 MB
  unsigned short* MT   = (unsigned short*)(ws + 174604288);    //   4 MB  (end ~179 MB)
  unsigned short* Qp   = xyb;                                  // xyb dead after gemm<0>

  prep_w<<<dim3(8, 8, 4), 256, 0, stream>>>(Wk, Wq, Wv, Wr, Wt);
  prep_xy<<<2048, 256, 0, stream>>>(x, y, xb, yb, xyb);
  gemm_bf16<0><<<1024, 256, 0, stream>>>(xyb, Wt, bk, KeT);
  ssum<<<4096, 256, 0, stream>>>(KeT, S);
  gemm_bf16<2><<<1024, 256, 0, stream>>>(xb, Wt + 2 * 262144, bv, VT);
  gemm_bf16<1><<<1024, 256, 0, stream>>>(yb, Wt + 262144, bq, Qp);
  context_partial<<<dim3(4, 8, 8), 256, 0, stream>>>(KeT, VT, cp);
  ctx_reduce<<<64, 256, 0, stream>>>(cp, S, ctxN);
  ctx_mm<<<dim3(8, 8), 256, 0, stream>>>(ctxN, Wt + 3 * 262144, MT);
  gemm_bf16<3><<<1024, 256, 0, stream>>>(Qp, MT, br, out);
}